// Round 18
// baseline (65.043 us; speedup 1.0000x reference)
//
#include <hip/hip_runtime.h>
#include <math.h>

#define NROWS 8192
#define NCLS  5994
#define NCLSP 6144   // padded class rows (zero W rows -> cosine 0)
#define NPAD  (NCLSP - NCLS)
#define KDIM  192
#define PITCHB 384   // bytes per class row of Whi (192 * 2B)
#define SSC   30.0f
#define COSM  0.9800665778412416f
#define SINM  0.19866933079506122f
#define THRV  (-0.9800665778412416f)
#define MMV   0.03973386615901225f
#define NCG   8
#define CPG   768    // classes per class-group (persistent blocks)
#define NPH   12     // phases of 64 classes (2 tiles) each
#define XSCALE 2048.0f
#define XINV   (1.0f / 2048.0f)
#define GAPS   0.6144f   // 3e-4 cosine gap, in 2048-scaled units
#define FIXROWS 16
#define FIXWIN  24
#define FIXCPW  256
// exp(30c-30) = exp2(E2A*acc + E2B) with acc = 2048*cosine
#define E2A (43.2808512266689f / 2048.0f)
#define E2B (-43.2808512266689f)

typedef float f32x4 __attribute__((ext_vector_type(4)));
typedef _Float16 f16x8 __attribute__((ext_vector_type(8)));

typedef const __attribute__((address_space(1))) unsigned int* gp32_t;
typedef __attribute__((address_space(3))) unsigned int* lp32_t;
__device__ __forceinline__ void gload16(const void* g, void* l) {
  __builtin_amdgcn_global_load_lds((gp32_t)g, (lp32_t)l, 16, 0, 0);
}

// single-instruction 2^x (args in [-87,0] -> normal results; exact enough here)
__device__ __forceinline__ float fast_exp2(float x) {
  float r;
  asm("v_exp_f32 %0, %1" : "=v"(r) : "v"(x));
  return r;
}

// ---------- fused prep: W rows [0,6144) normalize->fp16; x rows ->fp16 (x2048) ----------
__global__ __launch_bounds__(256) void prep(
    const float* __restrict__ x, const float* __restrict__ W,
    _Float16* __restrict__ Xhi, _Float16* __restrict__ Whi,
    float* __restrict__ rnw, int* __restrict__ nflag, int* __restrict__ done) {
  if (blockIdx.x == 0 && threadIdx.x == 0) { *nflag = 0; *done = 0; }
  const int lane = threadIdx.x & 63;
  const int sub = threadIdx.x >> 6;
  if (blockIdx.x < NCLSP / 4) {
    const int r = blockIdx.x * 4 + sub;
    _Float16* o = Whi + (size_t)r * KDIM;
    if (r >= NCLS) {
      #pragma unroll
      for (int j = 0; j < 3; ++j) o[lane + j * 64] = (_Float16)0.f;
      if (lane == 0) rnw[r] = 0.f;
      return;
    }
    const float* w = W + (size_t)r * KDIM;
    float e0 = w[lane], e1 = w[lane + 64], e2 = w[lane + 128];
    float ss = e0 * e0 + e1 * e1 + e2 * e2;
    #pragma unroll
    for (int m = 1; m < 64; m <<= 1) ss += __shfl_xor(ss, m);
    const float rn = 1.0f / fmaxf(sqrtf(ss), 1e-12f);
    o[lane] = (_Float16)(e0 * rn);
    o[lane + 64] = (_Float16)(e1 * rn);
    o[lane + 128] = (_Float16)(e2 * rn);
    if (lane == 0) rnw[r] = rn;
  } else {
    const int r = (blockIdx.x - NCLSP / 4) * 4 + sub;
    const float* xr = x + (size_t)r * KDIM;
    float e0 = xr[lane], e1 = xr[lane + 64], e2 = xr[lane + 128];
    float ss = e0 * e0 + e1 * e1 + e2 * e2;
    #pragma unroll
    for (int m = 1; m < 64; m <<= 1) ss += __shfl_xor(ss, m);
    const float rn = 1.0f / fmaxf(sqrtf(ss), 1e-12f);
    const float sc = rn * XSCALE;
    Xhi[(size_t)r * KDIM + lane] = (_Float16)(e0 * sc);
    Xhi[(size_t)r * KDIM + lane + 64] = (_Float16)(e1 * sc);
    Xhi[(size_t)r * KDIM + lane + 128] = (_Float16)(e2 * sc);
  }
}

// ---------- main: fp16 MFMA cosine, persistent blocks, 64-class phases ----------
__global__ __launch_bounds__(256, 2) void arc_main(
    const _Float16* __restrict__ Xhi, const _Float16* __restrict__ Whi,
    float* __restrict__ s_part, float* __restrict__ b1p) {
  __shared__ __align__(16) char lds[2][24576];
  const int tid = threadIdx.x;
  const int wave = tid >> 6, lane = tid & 63;
  const int col = lane & 15, kb = lane >> 4;
  const int swz = (col & 7) << 4;
  const int r0w = (blockIdx.x * 4 + wave) * 32;
  const int c0g = blockIdx.y * CPG;

  // resident A fragments: 32 rows x 192 k (loaded once, reused for 768 classes)
  f16x8 ahi[2][6];
  #pragma unroll
  for (int mf = 0; mf < 2; ++mf)
    #pragma unroll
    for (int ks = 0; ks < 6; ++ks)
      ahi[mf][ks] = *(const f16x8*)(Xhi + (size_t)(r0w + mf * 16 + col) * KDIM + ks * 32 + kb * 8);

  // staging: linear LDS dest, inverse-swizzled global source (64 classes x 384B/phase)
  int soff[6];
  #pragma unroll
  for (int j = 0; j < 6; ++j) {
    int q = tid + j * 256;
    int rr = q / 24, cc = q % 24;
    soff[j] = rr * PITCHB + ((cc * 16) ^ ((rr & 7) << 4));
  }
  const char* gbase = (const char*)Whi + (size_t)c0g * PITCHB;
  // prologue: stage phase 0 (64 classes)
  #pragma unroll
  for (int j = 0; j < 6; ++j) gload16(gbase + soff[j], &lds[0][j * 4096 + tid * 16]);

  float sacc[8], v1[8];
  #pragma unroll
  for (int s = 0; s < 8; ++s) { sacc[s] = 0.f; v1[s] = -1e30f; }
  const f32x4 z4 = {0.f, 0.f, 0.f, 0.f};

  for (int p = 0; p < NPH; ++p) {
    // drain this phase's loads (issued one full compute phase ago), then barrier.
    asm volatile("s_waitcnt vmcnt(0)" ::: "memory");
    __builtin_amdgcn_s_barrier();
    asm volatile("" ::: "memory");   // pin: stage must not hoist above barrier
    if (p + 1 < NPH) {  // stage next phase into the buffer everyone just finished
      const char* g = gbase + (size_t)(p + 1) * 64 * PITCHB;
      char* l = &lds[(p + 1) & 1][0];
      #pragma unroll
      for (int j = 0; j < 6; ++j) gload16(g + soff[j], l + j * 4096 + tid * 16);
    }
    #pragma unroll
    for (int h = 0; h < 2; ++h) {   // two 32-class tiles per phase
      const char* base = &lds[p & 1][h * 12288];
      f32x4 acc[2][2];
      #pragma unroll
      for (int ks = 0; ks < 6; ++ks) {
        #pragma unroll
        for (int cg = 0; cg < 2; ++cg) {
          f16x8 b = *(const f16x8*)(base + (col + cg * 16) * PITCHB + ((ks * 64 + kb * 16) ^ swz));
          #pragma unroll
          for (int mf = 0; mf < 2; ++mf) {
            if (ks == 0) acc[cg][mf] = __builtin_amdgcn_mfma_f32_16x16x32_f16(ahi[mf][0], b, z4, 0, 0, 0);
            else         acc[cg][mf] = __builtin_amdgcn_mfma_f32_16x16x32_f16(ahi[mf][ks], b, acc[cg][mf], 0, 0, 0);
          }
        }
      }
      #pragma unroll
      for (int cg = 0; cg < 2; ++cg)
        #pragma unroll
        for (int mf = 0; mf < 2; ++mf)
          #pragma unroll
          for (int e = 0; e < 4; ++e) {
            const int s = mf * 4 + e;
            const float c = acc[cg][mf][e];           // = 2048 * cosine
            sacc[s] += fast_exp2(fmaf(E2A, c, E2B));  // exp(30*cos - 30)
            v1[s] = fmaxf(v1[s], c);
          }
    }
  }

  // reduce across the 16 class-columns (lane bits 0-3)
  #pragma unroll
  for (int m = 1; m < 16; m <<= 1) {
    #pragma unroll
    for (int s = 0; s < 8; ++s) {
      sacc[s] += __shfl_xor(sacc[s], m);
      v1[s] = fmaxf(v1[s], __shfl_xor(v1[s], m));
    }
  }
  if (col == 0) {
    #pragma unroll
    for (int s = 0; s < 8; ++s) {
      int row = r0w + (s >> 2) * 16 + kb * 4 + (s & 3);
      size_t o = (size_t)row * NCG + blockIdx.y;
      s_part[o] = sacc[s];
      b1p[o] = v1[s];   // scaled (2048*cosine)
    }
  }
}

// ---------- merge: per-block loss partials (deterministic), flag ambiguous rows ----------
__global__ __launch_bounds__(256) void arc_merge(
    const _Float16* __restrict__ Xhi, const _Float16* __restrict__ Whi,
    const int* __restrict__ labels, const float* __restrict__ s_part,
    const float* __restrict__ b1p, int* __restrict__ nflag,
    int* __restrict__ list, unsigned long long* __restrict__ keybuf,
    double* __restrict__ pl) {
  __shared__ double red[4];
  const int tid = threadIdx.x;
  const int wave = tid >> 6, lane = tid & 63;
  double lsum = 0.0;
  #pragma unroll 1
  for (int i = 0; i < 8; ++i) {
    const int r = blockIdx.x * 32 + wave * 8 + i;
    const int y = labels[r];
    const _Float16* xh = Xhi + (size_t)r * KDIM;
    const _Float16* wh = Whi + (size_t)y * KDIM;
    float ay = (float)xh[lane] * (float)wh[lane]
             + (float)xh[lane + 64] * (float)wh[lane + 64]
             + (float)xh[lane + 128] * (float)wh[lane + 128];
    #pragma unroll
    for (int m = 1; m < 64; m <<= 1) ay += __shfl_xor(ay, m);
    float ps = 0.f, pv1 = -1e30f;
    if (lane < NCG) {
      size_t o = (size_t)r * NCG + lane;
      ps = s_part[o]; pv1 = b1p[o];
    }
    #pragma unroll
    for (int m = 1; m < NCG; m <<= 1) {
      ps += __shfl_xor(ps, m);
      pv1 = fmaxf(pv1, __shfl_xor(pv1, m));
    }
    if (lane == 0) {
      const float cy = ay * XINV;   // approx cosine; loss err ~0.008 << 0.3375
      const float sine = sqrtf(fmaxf(0.f, 1.f - cy * cy));
      const float cp = (cy > THRV) ? (cy * COSM - sine * SINM) : (cy - MMV);
      const float zy = SSC * cp, zy0 = SSC * cy;
      const float s2 = ps - (float)NPAD * __expf(-SSC) - __expf(zy0 - SSC) + __expf(zy - SSC);
      lsum += (double)(SSC + logf(s2) - zy);
      if (pv1 - ay < GAPS) {   // label may be argmax: exact fixup decides
        int sl = atomicAdd(nflag, 1);
        list[sl] = r;
        keybuf[r] = 0ull;
      }
    }
  }
  if (lane == 0) red[wave] = lsum;
  __syncthreads();
  if (tid == 0) pl[blockIdx.x] = (red[0] + red[1]) + (red[2] + red[3]);
}

// ---------- fixup + fused final: exact argmax for flagged rows; last block reduces ----------
__global__ __launch_bounds__(256) void arc_fixup(
    const float* __restrict__ x, const float* __restrict__ W,
    const float* __restrict__ rnw, const int* __restrict__ nflag,
    const int* __restrict__ list, unsigned long long* __restrict__ keybuf,
    const double* __restrict__ pl, int* __restrict__ done,
    const int* __restrict__ labels, float* __restrict__ out) {
  __shared__ float4 xs[FIXROWS][48];
  __shared__ double redl[256];
  __shared__ int redc[256];
  __shared__ int isLast;
  const int tid = threadIdx.x;
  const int lane = tid & 63;
  const int nf = *nflag;
  const int ngroups = (nf + FIXROWS - 1) / FIXROWS;
  const int nit = ngroups * FIXWIN;
  for (int it = blockIdx.x; it < nit; it += gridDim.x) {
    const int fc = it / FIXWIN, win = it % FIXWIN;
    __syncthreads();
    for (int q = tid; q < FIXROWS * 48; q += 256) {
      int i = q / 48, k4 = q % 48;
      int fi = fc * FIXROWS + i;
      int rr = list[fi < nf ? fi : 0];
      xs[i][k4] = ((const float4*)x)[(size_t)rr * 48 + k4];
    }
    __syncthreads();
    const int c = win * FIXCPW + tid;
    const bool valid = c < NCLS;
    const int cc = valid ? c : 0;
    const float4* wc = (const float4*)(W + (size_t)cc * KDIM);
    const float rw = rnw[cc];
    #pragma unroll 1
    for (int rg = 0; rg < 2; ++rg) {
      float a[8];
      #pragma unroll
      for (int i = 0; i < 8; ++i) a[i] = 0.f;
      #pragma unroll 4
      for (int k4 = 0; k4 < 48; ++k4) {
        float4 wv = wc[k4];
        #pragma unroll
        for (int i = 0; i < 8; ++i) {
          float4 xv = xs[rg * 8 + i][k4];
          a[i] = fmaf(wv.x, xv.x, fmaf(wv.y, xv.y, fmaf(wv.z, xv.z, fmaf(wv.w, xv.w, a[i]))));
        }
      }
      #pragma unroll 1
      for (int i = 0; i < 8; ++i) {
        float v = a[i] * rw;   // argmax invariant to positive row scale
        unsigned int ub = __float_as_uint(v);
        unsigned int k32 = (v < 0.f) ? ~ub : (ub | 0x80000000u);
        unsigned long long key =
            valid ? (((unsigned long long)k32 << 32) | (unsigned int)(8191 - c)) : 0ull;
        #pragma unroll
        for (int m = 1; m < 64; m <<= 1) {
          unsigned long long o = __shfl_xor(key, m);
          key = o > key ? o : key;
        }
        const int fi = fc * FIXROWS + rg * 8 + i;
        if (lane == 0 && fi < nf) atomicMax(&keybuf[list[fi]], key);
      }
    }
  }
  // ---- fused final: last block to finish performs the deterministic reduction ----
  __threadfence();
  __syncthreads();
  if (tid == 0) isLast = (atomicAdd(done, 1) == (int)gridDim.x - 1) ? 1 : 0;
  __syncthreads();
  if (isLast) {
    __threadfence();   // acquire: all blocks' keybuf atomics visible
    int add = 0;
    for (int i = tid; i < nf; i += 256) {
      int r = list[i];
      int cls = 8191 - (int)(keybuf[r] & 0xffffffffull);
      add += (cls == labels[r]) ? 1 : 0;
    }
    redl[tid] = pl[tid];
    redc[tid] = add;
    __syncthreads();
    for (int st = 128; st > 0; st >>= 1) {
      if (tid < st) { redl[tid] += redl[tid + st]; redc[tid] += redc[tid + st]; }
      __syncthreads();
    }
    if (tid == 0) {
      out[0] = (float)(redl[0] / (double)NROWS);
      out[1] = (float)redc[0];
    }
  }
}

extern "C" void kernel_launch(void* const* d_in, const int* in_sizes, int n_in,
                              void* d_out, int out_size, void* d_ws, size_t ws_size,
                              hipStream_t stream) {
  const float* x = (const float*)d_in[0];
  const int* labels = (const int*)d_in[1];
  const float* W = (const float*)d_in[2];
  float* out = (float*)d_out;
  char* ws = (char*)d_ws;

  size_t off = 0;
  _Float16* Whi = (_Float16*)(ws + off); off += (size_t)NCLSP * KDIM * 2;
  _Float16* Xhi = (_Float16*)(ws + off); off += (size_t)NROWS * KDIM * 2;
  float* rnw = (float*)(ws + off);       off += (size_t)NCLSP * 4;
  float* s_part = (float*)(ws + off);    off += (size_t)NROWS * NCG * 4;
  float* b1p = (float*)(ws + off);       off += (size_t)NROWS * NCG * 4;
  unsigned long long* keybuf = (unsigned long long*)(ws + off); off += (size_t)NROWS * 8;
  int* list = (int*)(ws + off);          off += (size_t)NROWS * 4;
  int* nflag = (int*)(ws + off);         off += 64;
  int* done = (int*)(ws + off);          off += 64;
  double* pl = (double*)(ws + off);      off += 256 * 8;

  hipLaunchKernelGGL(prep, dim3(NCLSP / 4 + NROWS / 4), dim3(256), 0, stream,
                     x, W, Xhi, Whi, rnw, nflag, done);
  hipLaunchKernelGGL(arc_main, dim3(64, NCG), dim3(256), 0, stream, Xhi, Whi,
                     s_part, b1p);
  hipLaunchKernelGGL(arc_merge, dim3(256), dim3(256), 0, stream, Xhi, Whi,
                     labels, s_part, b1p, nflag, list, keybuf, pl);
  hipLaunchKernelGGL(arc_fixup, dim3(256), dim3(256), 0, stream, x, W, rnw, nflag,
                     list, keybuf, pl, done, labels, out);
}

// Round 19
// 48.377 us; speedup vs baseline: 1.3445x; 1.3445x over previous
//
#include <hip/hip_runtime.h>
#include <math.h>

#define NROWS 8192
#define NCLS  5994
#define NCLSP 6144   // padded class rows (zero W rows -> cosine 0)
#define NPAD  (NCLSP - NCLS)
#define KDIM  192
#define PITCHB 384   // bytes per class row of Whi (192 * 2B)
#define SSC   30.0f
#define COSM  0.9800665778412416f
#define SINM  0.19866933079506122f
#define THRV  (-0.9800665778412416f)
#define MMV   0.03973386615901225f
#define NCG   8
#define CPG   768    // classes per class-group (persistent blocks)
#define NPH   12     // phases of 64 classes (2 tiles) each
#define XSCALE 2048.0f
#define XINV   (1.0f / 2048.0f)
#define GAPS   0.6144f   // 3e-4 cosine gap, in 2048-scaled units
#define FIXROWS 16
#define FIXWIN  24
#define FIXCPW  256
// exp(30c-30) = exp2(E2A*acc + E2B) with acc = 2048*cosine
#define E2A (43.2808512266689f / 2048.0f)
#define E2B (-43.2808512266689f)

typedef float f32x4 __attribute__((ext_vector_type(4)));
typedef _Float16 f16x8 __attribute__((ext_vector_type(8)));

typedef const __attribute__((address_space(1))) unsigned int* gp32_t;
typedef __attribute__((address_space(3))) unsigned int* lp32_t;
__device__ __forceinline__ void gload16(const void* g, void* l) {
  __builtin_amdgcn_global_load_lds((gp32_t)g, (lp32_t)l, 16, 0, 0);
}

// single-instruction 2^x (args in [-87,0] -> normal results; exact enough here)
__device__ __forceinline__ float fast_exp2(float x) {
  float r;
  asm("v_exp_f32 %0, %1" : "=v"(r) : "v"(x));
  return r;
}

// ---------- fused prep: W rows [0,6144) normalize->fp16; x rows ->fp16 (x2048) ----------
__global__ __launch_bounds__(256) void prep(
    const float* __restrict__ x, const float* __restrict__ W,
    _Float16* __restrict__ Xhi, _Float16* __restrict__ Whi,
    float* __restrict__ rnw, int* __restrict__ nflag) {
  if (blockIdx.x == 0 && threadIdx.x == 0) *nflag = 0;
  const int lane = threadIdx.x & 63;
  const int sub = threadIdx.x >> 6;
  if (blockIdx.x < NCLSP / 4) {
    const int r = blockIdx.x * 4 + sub;
    _Float16* o = Whi + (size_t)r * KDIM;
    if (r >= NCLS) {
      #pragma unroll
      for (int j = 0; j < 3; ++j) o[lane + j * 64] = (_Float16)0.f;
      if (lane == 0) rnw[r] = 0.f;
      return;
    }
    const float* w = W + (size_t)r * KDIM;
    float e0 = w[lane], e1 = w[lane + 64], e2 = w[lane + 128];
    float ss = e0 * e0 + e1 * e1 + e2 * e2;
    #pragma unroll
    for (int m = 1; m < 64; m <<= 1) ss += __shfl_xor(ss, m);
    const float rn = 1.0f / fmaxf(sqrtf(ss), 1e-12f);
    o[lane] = (_Float16)(e0 * rn);
    o[lane + 64] = (_Float16)(e1 * rn);
    o[lane + 128] = (_Float16)(e2 * rn);
    if (lane == 0) rnw[r] = rn;
  } else {
    const int r = (blockIdx.x - NCLSP / 4) * 4 + sub;
    const float* xr = x + (size_t)r * KDIM;
    float e0 = xr[lane], e1 = xr[lane + 64], e2 = xr[lane + 128];
    float ss = e0 * e0 + e1 * e1 + e2 * e2;
    #pragma unroll
    for (int m = 1; m < 64; m <<= 1) ss += __shfl_xor(ss, m);
    const float rn = 1.0f / fmaxf(sqrtf(ss), 1e-12f);
    const float sc = rn * XSCALE;
    Xhi[(size_t)r * KDIM + lane] = (_Float16)(e0 * sc);
    Xhi[(size_t)r * KDIM + lane + 64] = (_Float16)(e1 * sc);
    Xhi[(size_t)r * KDIM + lane + 128] = (_Float16)(e2 * sc);
  }
}

// ---------- main: fp16 MFMA cosine, persistent blocks, 64-class phases ----------
__global__ __launch_bounds__(256, 2) void arc_main(
    const _Float16* __restrict__ Xhi, const _Float16* __restrict__ Whi,
    float* __restrict__ s_part, float* __restrict__ b1p) {
  __shared__ __align__(16) char lds[2][24576];
  const int tid = threadIdx.x;
  const int wave = tid >> 6, lane = tid & 63;
  const int col = lane & 15, kb = lane >> 4;
  const int swz = (col & 7) << 4;
  const int r0w = (blockIdx.x * 4 + wave) * 32;
  const int c0g = blockIdx.y * CPG;

  // resident A fragments: 32 rows x 192 k (loaded once, reused for 768 classes)
  f16x8 ahi[2][6];
  #pragma unroll
  for (int mf = 0; mf < 2; ++mf)
    #pragma unroll
    for (int ks = 0; ks < 6; ++ks)
      ahi[mf][ks] = *(const f16x8*)(Xhi + (size_t)(r0w + mf * 16 + col) * KDIM + ks * 32 + kb * 8);

  // staging: linear LDS dest, inverse-swizzled global source (64 classes x 384B/phase)
  int soff[6];
  #pragma unroll
  for (int j = 0; j < 6; ++j) {
    int q = tid + j * 256;
    int rr = q / 24, cc = q % 24;
    soff[j] = rr * PITCHB + ((cc * 16) ^ ((rr & 7) << 4));
  }
  const char* gbase = (const char*)Whi + (size_t)c0g * PITCHB;
  // prologue: stage phase 0 (64 classes)
  #pragma unroll
  for (int j = 0; j < 6; ++j) gload16(gbase + soff[j], &lds[0][j * 4096 + tid * 16]);

  float sacc[8], v1[8];
  #pragma unroll
  for (int s = 0; s < 8; ++s) { sacc[s] = 0.f; v1[s] = -1e30f; }
  const f32x4 z4 = {0.f, 0.f, 0.f, 0.f};

  for (int p = 0; p < NPH; ++p) {
    // drain this phase's loads (issued one full compute phase ago), then barrier.
    asm volatile("s_waitcnt vmcnt(0)" ::: "memory");
    __builtin_amdgcn_s_barrier();
    asm volatile("" ::: "memory");   // pin: stage must not hoist above barrier
    if (p + 1 < NPH) {  // stage next phase into the buffer everyone just finished
      const char* g = gbase + (size_t)(p + 1) * 64 * PITCHB;
      char* l = &lds[(p + 1) & 1][0];
      #pragma unroll
      for (int j = 0; j < 6; ++j) gload16(g + soff[j], l + j * 4096 + tid * 16);
    }
    #pragma unroll
    for (int h = 0; h < 2; ++h) {   // two 32-class tiles per phase
      const char* base = &lds[p & 1][h * 12288];
      f32x4 acc[2][2];
      #pragma unroll
      for (int ks = 0; ks < 6; ++ks) {
        #pragma unroll
        for (int cg = 0; cg < 2; ++cg) {
          f16x8 b = *(const f16x8*)(base + (col + cg * 16) * PITCHB + ((ks * 64 + kb * 16) ^ swz));
          #pragma unroll
          for (int mf = 0; mf < 2; ++mf) {
            if (ks == 0) acc[cg][mf] = __builtin_amdgcn_mfma_f32_16x16x32_f16(ahi[mf][0], b, z4, 0, 0, 0);
            else         acc[cg][mf] = __builtin_amdgcn_mfma_f32_16x16x32_f16(ahi[mf][ks], b, acc[cg][mf], 0, 0, 0);
          }
        }
      }
      #pragma unroll
      for (int cg = 0; cg < 2; ++cg)
        #pragma unroll
        for (int mf = 0; mf < 2; ++mf)
          #pragma unroll
          for (int e = 0; e < 4; ++e) {
            const int s = mf * 4 + e;
            const float c = acc[cg][mf][e];           // = 2048 * cosine
            sacc[s] += fast_exp2(fmaf(E2A, c, E2B));  // exp(30*cos - 30)
            v1[s] = fmaxf(v1[s], c);
          }
    }
  }

  // reduce across the 16 class-columns (lane bits 0-3)
  #pragma unroll
  for (int m = 1; m < 16; m <<= 1) {
    #pragma unroll
    for (int s = 0; s < 8; ++s) {
      sacc[s] += __shfl_xor(sacc[s], m);
      v1[s] = fmaxf(v1[s], __shfl_xor(v1[s], m));
    }
  }
  if (col == 0) {
    #pragma unroll
    for (int s = 0; s < 8; ++s) {
      int row = r0w + (s >> 2) * 16 + kb * 4 + (s & 3);
      size_t o = (size_t)row * NCG + blockIdx.y;
      s_part[o] = sacc[s];
      b1p[o] = v1[s];   // scaled (2048*cosine)
    }
  }
}

// ---------- merge: per-block loss partials (deterministic), flag ambiguous rows ----------
__global__ __launch_bounds__(256) void arc_merge(
    const _Float16* __restrict__ Xhi, const _Float16* __restrict__ Whi,
    const int* __restrict__ labels, const float* __restrict__ s_part,
    const float* __restrict__ b1p, int* __restrict__ nflag,
    int* __restrict__ list, unsigned long long* __restrict__ keybuf,
    double* __restrict__ pl) {
  __shared__ double red[4];
  const int tid = threadIdx.x;
  const int wave = tid >> 6, lane = tid & 63;
  double lsum = 0.0;
  #pragma unroll 1
  for (int i = 0; i < 8; ++i) {
    const int r = blockIdx.x * 32 + wave * 8 + i;
    const int y = labels[r];
    const _Float16* xh = Xhi + (size_t)r * KDIM;
    const _Float16* wh = Whi + (size_t)y * KDIM;
    float ay = (float)xh[lane] * (float)wh[lane]
             + (float)xh[lane + 64] * (float)wh[lane + 64]
             + (float)xh[lane + 128] * (float)wh[lane + 128];
    #pragma unroll
    for (int m = 1; m < 64; m <<= 1) ay += __shfl_xor(ay, m);
    float ps = 0.f, pv1 = -1e30f;
    if (lane < NCG) {
      size_t o = (size_t)r * NCG + lane;
      ps = s_part[o]; pv1 = b1p[o];
    }
    #pragma unroll
    for (int m = 1; m < NCG; m <<= 1) {
      ps += __shfl_xor(ps, m);
      pv1 = fmaxf(pv1, __shfl_xor(pv1, m));
    }
    if (lane == 0) {
      const float cy = ay * XINV;   // approx cosine; loss err ~0.008 << 0.3375
      const float sine = sqrtf(fmaxf(0.f, 1.f - cy * cy));
      const float cp = (cy > THRV) ? (cy * COSM - sine * SINM) : (cy - MMV);
      const float zy = SSC * cp, zy0 = SSC * cy;
      const float s2 = ps - (float)NPAD * __expf(-SSC) - __expf(zy0 - SSC) + __expf(zy - SSC);
      lsum += (double)(SSC + logf(s2) - zy);
      if (pv1 - ay < GAPS) {   // label may be argmax: exact fixup decides
        int sl = atomicAdd(nflag, 1);
        list[sl] = r;
        keybuf[r] = 0ull;
      }
    }
  }
  if (lane == 0) red[wave] = lsum;
  __syncthreads();
  if (tid == 0) pl[blockIdx.x] = (red[0] + red[1]) + (red[2] + red[3]);
}

// ---------- fixup: exact fp32 argmax for flagged rows (16-row W reuse) ----------
__global__ __launch_bounds__(256) void arc_fixup(
    const float* __restrict__ x, const float* __restrict__ W,
    const float* __restrict__ rnw, const int* __restrict__ nflag,
    const int* __restrict__ list, unsigned long long* __restrict__ keybuf) {
  __shared__ float4 xs[FIXROWS][48];
  const int tid = threadIdx.x;
  const int lane = tid & 63;
  const int nf = *nflag;
  const int ngroups = (nf + FIXROWS - 1) / FIXROWS;
  const int nit = ngroups * FIXWIN;
  for (int it = blockIdx.x; it < nit; it += gridDim.x) {
    const int fc = it / FIXWIN, win = it % FIXWIN;
    __syncthreads();
    for (int q = tid; q < FIXROWS * 48; q += 256) {
      int i = q / 48, k4 = q % 48;
      int fi = fc * FIXROWS + i;
      int rr = list[fi < nf ? fi : 0];
      xs[i][k4] = ((const float4*)x)[(size_t)rr * 48 + k4];
    }
    __syncthreads();
    const int c = win * FIXCPW + tid;
    const bool valid = c < NCLS;
    const int cc = valid ? c : 0;
    const float4* wc = (const float4*)(W + (size_t)cc * KDIM);
    const float rw = rnw[cc];
    #pragma unroll 1
    for (int rg = 0; rg < 2; ++rg) {
      float a[8];
      #pragma unroll
      for (int i = 0; i < 8; ++i) a[i] = 0.f;
      #pragma unroll 4
      for (int k4 = 0; k4 < 48; ++k4) {
        float4 wv = wc[k4];
        #pragma unroll
        for (int i = 0; i < 8; ++i) {
          float4 xv = xs[rg * 8 + i][k4];
          a[i] = fmaf(wv.x, xv.x, fmaf(wv.y, xv.y, fmaf(wv.z, xv.z, fmaf(wv.w, xv.w, a[i]))));
        }
      }
      #pragma unroll 1
      for (int i = 0; i < 8; ++i) {
        float v = a[i] * rw;   // argmax invariant to positive row scale
        unsigned int ub = __float_as_uint(v);
        unsigned int k32 = (v < 0.f) ? ~ub : (ub | 0x80000000u);
        unsigned long long key =
            valid ? (((unsigned long long)k32 << 32) | (unsigned int)(8191 - c)) : 0ull;
        #pragma unroll
        for (int m = 1; m < 64; m <<= 1) {
          unsigned long long o = __shfl_xor(key, m);
          key = o > key ? o : key;
        }
        const int fi = fc * FIXROWS + rg * 8 + i;
        if (lane == 0 && fi < nf) atomicMax(&keybuf[list[fi]], key);
      }
    }
  }
}

// ---------- final: reduce 256 loss partials + resolve flagged rows ----------
__global__ __launch_bounds__(256) void arc_final(
    const double* __restrict__ pl, const int* __restrict__ nflag,
    const int* __restrict__ list, const unsigned long long* __restrict__ keybuf,
    const int* __restrict__ labels, float* __restrict__ out) {
  __shared__ double redl[256];
  __shared__ int redc[256];
  const int tid = threadIdx.x;
  const int nf = *nflag;
  int add = 0;
  for (int i = tid; i < nf; i += 256) {
    int r = list[i];
    int cls = 8191 - (int)(keybuf[r] & 0xffffffffull);
    add += (cls == labels[r]) ? 1 : 0;
  }
  redl[tid] = pl[tid];
  redc[tid] = add;
  __syncthreads();
  for (int st = 128; st > 0; st >>= 1) {
    if (tid < st) { redl[tid] += redl[tid + st]; redc[tid] += redc[tid + st]; }
    __syncthreads();
  }
  if (tid == 0) {
    out[0] = (float)(redl[0] / (double)NROWS);
    out[1] = (float)redc[0];
  }
}

extern "C" void kernel_launch(void* const* d_in, const int* in_sizes, int n_in,
                              void* d_out, int out_size, void* d_ws, size_t ws_size,
                              hipStream_t stream) {
  const float* x = (const float*)d_in[0];
  const int* labels = (const int*)d_in[1];
  const float* W = (const float*)d_in[2];
  float* out = (float*)d_out;
  char* ws = (char*)d_ws;

  size_t off = 0;
  _Float16* Whi = (_Float16*)(ws + off); off += (size_t)NCLSP * KDIM * 2;
  _Float16* Xhi = (_Float16*)(ws + off); off += (size_t)NROWS * KDIM * 2;
  float* rnw = (float*)(ws + off);       off += (size_t)NCLSP * 4;
  float* s_part = (float*)(ws + off);    off += (size_t)NROWS * NCG * 4;
  float* b1p = (float*)(ws + off);       off += (size_t)NROWS * NCG * 4;
  unsigned long long* keybuf = (unsigned long long*)(ws + off); off += (size_t)NROWS * 8;
  int* list = (int*)(ws + off);          off += (size_t)NROWS * 4;
  int* nflag = (int*)(ws + off);         off += 64;
  double* pl = (double*)(ws + off);      off += 256 * 8;

  hipLaunchKernelGGL(prep, dim3(NCLSP / 4 + NROWS / 4), dim3(256), 0, stream,
                     x, W, Xhi, Whi, rnw, nflag);
  hipLaunchKernelGGL(arc_main, dim3(64, NCG), dim3(256), 0, stream, Xhi, Whi,
                     s_part, b1p);
  hipLaunchKernelGGL(arc_merge, dim3(256), dim3(256), 0, stream, Xhi, Whi,
                     labels, s_part, b1p, nflag, list, keybuf, pl);
  hipLaunchKernelGGL(arc_fixup, dim3(256), dim3(256), 0, stream, x, W, rnw, nflag,
                     list, keybuf);
  hipLaunchKernelGGL(arc_final, dim3(1), dim3(256), 0, stream, pl, nflag, list,
                     keybuf, labels, out);
}